// Round 13
// baseline (167.320 us; speedup 1.0000x reference)
//
#include <hip/hip_runtime.h>
#include <math.h>

// VP-SDE Euler-Maruyama forward diffusion (fp32).
// out[0] = x; out[t+1] = a_t * out[t] + b_t * noise[t],  t = 0..99
//
// Ladder: R4 178.5 (f4 2-buf nt/nt) | R9 177.8 (f2 32w/CU) | cached/LDS/
// producer-consumer/deep-ILP 183-192 | R12 164.2 (chunk-major: wave=2KB
// contiguous/plane, 512 blocks -- DRAM row-locality theory CONFIRMED).
// R13: same lever, one variable: fuse the 2 co-resident 8KB block-tiles
// per CU into ONE 16KB tile. block=512 (8 waves), grid=256 (1 block/CU,
// 32/XCD). Per-thread code identical to R12; nt/nt; depth-4 pipeline.

#define S_STEPS 100
#define DEPTH 4                 // pipeline depth in planes

typedef float f32x4 __attribute__((ext_vector_type(4)));

__global__ __launch_bounds__(512) void vpsde_fwd_kernel(
    const f32x4* __restrict__ x,
    const f32x4* __restrict__ noise,
    f32x4* __restrict__ out,
    int ne4)  // float4 per plane (262,144)
{
    __shared__ float s_a[S_STEPS];
    __shared__ float s_b[S_STEPS];

    const int tid = threadIdx.x;
    if (tid < S_STEPS) {
        const float dt = 0.01f;
        float nt_ = (float)tid * dt;           // (t-1)/S for t=1..S
        float beta = 0.1f + nt_ * 19.9f;
        s_a[tid] = 1.0f - 0.5f * beta * dt;
        s_b[tid] = sqrtf(beta) * 0.1f;         // sqrt(beta)*sqrt(dt)
    }
    __syncthreads();

    const int wid  = tid >> 6;                 // 0..7
    const int lane = tid & 63;

    // Chunk-major: wave covers 128 consecutive float4 (2KB) per plane;
    // block (8 waves) covers 1024 float4 = 16KB contiguous per plane.
    const size_t base = (size_t)blockIdx.x * 1024 + (size_t)wid * 128 + lane;

    const f32x4* gl = noise + base;        // running load ptr (plane t)
    f32x4*       st = out + base + ne4;    // running store ptr (plane t+1)

    f32x4 xv0 = x[base];
    f32x4 xv1 = x[base + 64];
    __builtin_nontemporal_store(xv0, out + base);        // out[0] = x
    __builtin_nontemporal_store(xv1, out + base + 64);

    int t = 0;                              // current plane index

    f32x4 A[2], B[2], C[2], Dq[2];

    auto loadp = [&](f32x4* buf) {          // one plane: 2 contiguous loads
        buf[0] = __builtin_nontemporal_load(gl);
        buf[1] = __builtin_nontemporal_load(gl + 64);
        gl += ne4;
    };
    auto consume = [&](const f32x4* buf) {  // fma + 2 contiguous stores
        const float a = s_a[t];
        const float b = s_b[t];
        xv0 = a * xv0 + b * buf[0];
        xv1 = a * xv1 + b * buf[1];
        __builtin_nontemporal_store(xv0, st);
        __builtin_nontemporal_store(xv1, st + 64);
        st += ne4;
        ++t;
    };

    // Prologue: 4 planes in flight (8 loads, 8KB/wave).
    loadp(A); loadp(B); loadp(C); loadp(Dq);

    // 24 cycles x 4 planes = 96 consumed; planes 4..99 loaded on the fly.
    #pragma unroll 1
    for (int cyc = 0; cyc < (S_STEPS / DEPTH) - 1; ++cyc) {
        consume(A);  loadp(A);
        consume(B);  loadp(B);
        consume(C);  loadp(C);
        consume(Dq); loadp(Dq);
    }
    // Epilogue: planes 96..99.
    consume(A); consume(B); consume(C); consume(Dq);
}

extern "C" void kernel_launch(void* const* d_in, const int* in_sizes, int n_in,
                              void* d_out, int out_size, void* d_ws, size_t ws_size,
                              hipStream_t stream) {
    const float* x     = (const float*)d_in[0];   // (64,256,64)
    const float* noise = (const float*)d_in[1];   // (100,64,256,64)
    float* out         = (float*)d_out;           // (101,64,256,64)

    const int ne  = in_sizes[0];       // 1,048,576 floats per plane
    const int ne4 = ne / 4;            // 262,144 float4 per plane

    const int block = 512;             // 8 waves
    const int grid  = ne4 / 1024;      // 256 blocks -> 1/CU, 16KB tile/plane

    vpsde_fwd_kernel<<<grid, block, 0, stream>>>(
        (const f32x4*)x, (const f32x4*)noise, (f32x4*)out, ne4);
}

// Round 14
// 166.140 us; speedup vs baseline: 1.0071x; 1.0071x over previous
//
#include <hip/hip_runtime.h>
#include <math.h>

// VP-SDE Euler-Maruyama forward diffusion (fp32).
// out[0] = x; out[t+1] = a_t * out[t] + b_t * noise[t],  t = 0..99
//
// Ladder: R4 178.5 | R9 177.8 (32 w/CU) | cached/LDS/prod-cons 183-192 |
// R12 164.2 (2 chunks/thread, 2048 waves) | R13 167.3 (block-fusion: no gain
// -> block tile is NOT the lever; wave count is).
// Refined theory: barrier-free waves desync across the 100-plane sweep;
// each wave is an independent DRAM stream. Fewer+fatter waves -> fewer
// concurrent row streams. R14: 4 chunks/thread -> 1024 waves (4/CU), wave =
// 4KB contiguous per plane. Depth-4 pipeline: 16 loads (16KB) in flight/wave
// = 64KB/CU >> 12KB needed to cover HBM latency. nt/nt.

#define S_STEPS 100
#define DEPTH 4                 // pipeline depth in planes
#define CH 4                    // float4 chunks per thread

typedef float f32x4 __attribute__((ext_vector_type(4)));

__global__ __launch_bounds__(256) void vpsde_fwd_kernel(
    const f32x4* __restrict__ x,
    const f32x4* __restrict__ noise,
    f32x4* __restrict__ out,
    int ne4)  // float4 per plane (262,144)
{
    __shared__ float s_a[S_STEPS];
    __shared__ float s_b[S_STEPS];

    const int tid = threadIdx.x;
    if (tid < S_STEPS) {
        const float dt = 0.01f;
        float nt_ = (float)tid * dt;           // (t-1)/S for t=1..S
        float beta = 0.1f + nt_ * 19.9f;
        s_a[tid] = 1.0f - 0.5f * beta * dt;
        s_b[tid] = sqrtf(beta) * 0.1f;         // sqrt(beta)*sqrt(dt)
    }
    __syncthreads();

    const int wid  = tid >> 6;                 // 0..3
    const int lane = tid & 63;

    // Wave covers 256 consecutive float4 (4KB) per plane: lane + 64*c.
    // Block (4 waves) covers 1024 float4 = 16KB contiguous per plane.
    const size_t base = (size_t)blockIdx.x * 1024 + (size_t)wid * 256 + lane;

    const f32x4* gl = noise + base;        // running load ptr (plane t)
    f32x4*       st = out + base + ne4;    // running store ptr (plane t+1)

    f32x4 xv[CH];
    #pragma unroll
    for (int c = 0; c < CH; ++c) {
        xv[c] = x[base + 64 * c];
        __builtin_nontemporal_store(xv[c], out + base + 64 * c);  // out[0]=x
    }

    int t = 0;                              // current plane index

    f32x4 A[CH], B[CH], C[CH], Dq[CH];

    auto loadp = [&](f32x4* buf) {          // one plane: 4 contiguous loads
        #pragma unroll
        for (int c = 0; c < CH; ++c)
            buf[c] = __builtin_nontemporal_load(gl + 64 * c);
        gl += ne4;
    };
    auto consume = [&](const f32x4* buf) {  // fma + 4 contiguous stores
        const float a = s_a[t];
        const float b = s_b[t];
        #pragma unroll
        for (int c = 0; c < CH; ++c) {
            xv[c] = a * xv[c] + b * buf[c];
            __builtin_nontemporal_store(xv[c], st + 64 * c);
        }
        st += ne4;
        ++t;
    };

    // Prologue: 4 planes in flight (16 loads, 16KB/wave).
    loadp(A); loadp(B); loadp(C); loadp(Dq);

    // 24 cycles x 4 planes = 96 consumed; planes 4..99 loaded on the fly.
    #pragma unroll 1
    for (int cyc = 0; cyc < (S_STEPS / DEPTH) - 1; ++cyc) {
        consume(A);  loadp(A);
        consume(B);  loadp(B);
        consume(C);  loadp(C);
        consume(Dq); loadp(Dq);
    }
    // Epilogue: planes 96..99.
    consume(A); consume(B); consume(C); consume(Dq);
}

extern "C" void kernel_launch(void* const* d_in, const int* in_sizes, int n_in,
                              void* d_out, int out_size, void* d_ws, size_t ws_size,
                              hipStream_t stream) {
    const float* x     = (const float*)d_in[0];   // (64,256,64)
    const float* noise = (const float*)d_in[1];   // (100,64,256,64)
    float* out         = (float*)d_out;           // (101,64,256,64)

    const int ne  = in_sizes[0];       // 1,048,576 floats per plane
    const int ne4 = ne / 4;            // 262,144 float4 per plane

    const int block = 256;             // 4 waves
    const int grid  = ne4 / 1024;      // 256 blocks -> 1/CU, 16KB tile/plane

    vpsde_fwd_kernel<<<grid, block, 0, stream>>>(
        (const f32x4*)x, (const f32x4*)noise, (f32x4*)out, ne4);
}

// Round 15
// 165.247 us; speedup vs baseline: 1.0125x; 1.0054x over previous
//
#include <hip/hip_runtime.h>
#include <math.h>

// VP-SDE Euler-Maruyama forward diffusion (fp32).
// out[0] = x; out[t+1] = a_t * out[t] + b_t * noise[t],  t = 0..99
//
// Ladder: R4 178.5 | R9 177.8 | cached/LDS/prod-cons 183-192 | R12 164.2
// (2 chunks/thread, 2048 waves, 2KB/wave/plane -- row-locality win) |
// R13 167.3 (block fusion: dead) | R14 166.1 (4KB/wave: dead).
// All structural levers saturated at 164.2 = 4.92 TB/s (78% of copy).
// R15: the one untested cell on the best structure -- CACHED loads.
// R6 measured FETCH=202MB with cached reads (L3 keeps ~half the noise
// resident across graph replays; nt stores don't evict it). Prior cached
// tests lost only because those structures were latency-fragile; R12 has
// 5x latency-hiding margin. If HBM-throughput-bound: ~640MB/4.9TB/s ~ 135us.

#define S_STEPS 100
#define DEPTH 4                 // pipeline depth in planes

typedef float f32x4 __attribute__((ext_vector_type(4)));

__global__ __launch_bounds__(256) void vpsde_fwd_kernel(
    const f32x4* __restrict__ x,
    const f32x4* __restrict__ noise,
    f32x4* __restrict__ out,
    int ne4)  // float4 per plane (262,144)
{
    __shared__ float s_a[S_STEPS];
    __shared__ float s_b[S_STEPS];

    const int tid = threadIdx.x;
    if (tid < S_STEPS) {
        const float dt = 0.01f;
        float nt_ = (float)tid * dt;           // (t-1)/S for t=1..S
        float beta = 0.1f + nt_ * 19.9f;
        s_a[tid] = 1.0f - 0.5f * beta * dt;
        s_b[tid] = sqrtf(beta) * 0.1f;         // sqrt(beta)*sqrt(dt)
    }
    __syncthreads();

    const int wid  = tid >> 6;
    const int lane = tid & 63;

    // Chunk-major: wave covers 128 consecutive float4 (2KB) per plane.
    const size_t base = (size_t)blockIdx.x * 512 + (size_t)wid * 128 + lane;

    const f32x4* gl = noise + base;        // running load ptr (plane t)
    f32x4*       st = out + base + ne4;    // running store ptr (plane t+1)

    f32x4 xv0 = x[base];
    f32x4 xv1 = x[base + 64];
    __builtin_nontemporal_store(xv0, out + base);        // out[0] = x
    __builtin_nontemporal_store(xv1, out + base + 64);

    int t = 0;                              // current plane index

    f32x4 A[2], B[2], C[2], Dq[2];

    auto loadp = [&](f32x4* buf) {          // one plane: 2 CACHED loads
        buf[0] = gl[0];                     // L2/L3 allocate: harvest the
        buf[1] = gl[64];                    // cross-replay L3 residency
        gl += ne4;
    };
    auto consume = [&](const f32x4* buf) {  // fma + 2 contiguous nt stores
        const float a = s_a[t];
        const float b = s_b[t];
        xv0 = a * xv0 + b * buf[0];
        xv1 = a * xv1 + b * buf[1];
        __builtin_nontemporal_store(xv0, st);
        __builtin_nontemporal_store(xv1, st + 64);
        st += ne4;
        ++t;
    };

    // Prologue: 4 planes in flight (8 loads, 8KB/wave).
    loadp(A); loadp(B); loadp(C); loadp(Dq);

    // 24 cycles x 4 planes = 96 consumed; planes 4..99 loaded on the fly.
    #pragma unroll 1
    for (int cyc = 0; cyc < (S_STEPS / DEPTH) - 1; ++cyc) {
        consume(A);  loadp(A);
        consume(B);  loadp(B);
        consume(C);  loadp(C);
        consume(Dq); loadp(Dq);
    }
    // Epilogue: planes 96..99.
    consume(A); consume(B); consume(C); consume(Dq);
}

extern "C" void kernel_launch(void* const* d_in, const int* in_sizes, int n_in,
                              void* d_out, int out_size, void* d_ws, size_t ws_size,
                              hipStream_t stream) {
    const float* x     = (const float*)d_in[0];   // (64,256,64)
    const float* noise = (const float*)d_in[1];   // (100,64,256,64)
    float* out         = (float*)d_out;           // (101,64,256,64)

    const int ne  = in_sizes[0];       // 1,048,576 floats per plane
    const int ne4 = ne / 4;            // 262,144 float4 per plane

    const int block = 256;
    const int grid  = ne4 / 512;       // 512 blocks (block tile = 8KB/plane)

    vpsde_fwd_kernel<<<grid, block, 0, stream>>>(
        (const f32x4*)x, (const f32x4*)noise, (f32x4*)out, ne4);
}

// Round 16
// 161.796 us; speedup vs baseline: 1.0341x; 1.0213x over previous
//
#include <hip/hip_runtime.h>
#include <math.h>

// VP-SDE Euler-Maruyama forward diffusion (fp32).
// out[0] = x; out[t+1] = a_t * out[t] + b_t * noise[t],  t = 0..99
//
// Ladder: R4 178.5 | R9 177.8 | cached/LDS/prod-cons 183-192 | R12 164.2
// (chunk-major, 2KB/wave/plane) | R13/R14 block/wave fattening: dead |
// R15 165.2 (cached loads: FLAT despite L3 subsidy -> NOT HBM-BW-bound;
// cap is in the request path for this plane-strided mixed stream).
// R16: T1 XCD swizzle -- consecutive blockIdx round-robin across 8 XCDs,
// so each XCD's footprint is 32 scattered 8KB tiles/plane. Remap so XCD k
// owns a contiguous 512KB run of every plane: dtile = (bid&7)*64 + bid>>3
// (bijective: 512 % 8 == 0). Everything else identical to R12.

#define S_STEPS 100
#define DEPTH 4                 // pipeline depth in planes

typedef float f32x4 __attribute__((ext_vector_type(4)));

__global__ __launch_bounds__(256) void vpsde_fwd_kernel(
    const f32x4* __restrict__ x,
    const f32x4* __restrict__ noise,
    f32x4* __restrict__ out,
    int ne4)  // float4 per plane (262,144)
{
    __shared__ float s_a[S_STEPS];
    __shared__ float s_b[S_STEPS];

    const int tid = threadIdx.x;
    if (tid < S_STEPS) {
        const float dt = 0.01f;
        float nt_ = (float)tid * dt;           // (t-1)/S for t=1..S
        float beta = 0.1f + nt_ * 19.9f;
        s_a[tid] = 1.0f - 0.5f * beta * dt;
        s_b[tid] = sqrtf(beta) * 0.1f;         // sqrt(beta)*sqrt(dt)
    }
    __syncthreads();

    const int wid  = tid >> 6;
    const int lane = tid & 63;

    // XCD-aware swizzle: XCD (bid&7) owns contiguous data tiles.
    const int bid   = blockIdx.x;
    const int dtile = ((bid & 7) << 6) | (bid >> 3);   // bijective for 512

    // Chunk-major: wave covers 128 consecutive float4 (2KB) per plane.
    const size_t base = (size_t)dtile * 512 + (size_t)wid * 128 + lane;

    const f32x4* gl = noise + base;        // running load ptr (plane t)
    f32x4*       st = out + base + ne4;    // running store ptr (plane t+1)

    f32x4 xv0 = x[base];
    f32x4 xv1 = x[base + 64];
    __builtin_nontemporal_store(xv0, out + base);        // out[0] = x
    __builtin_nontemporal_store(xv1, out + base + 64);

    int t = 0;                              // current plane index

    f32x4 A[2], B[2], C[2], Dq[2];

    auto loadp = [&](f32x4* buf) {          // one plane: 2 contiguous loads
        buf[0] = __builtin_nontemporal_load(gl);
        buf[1] = __builtin_nontemporal_load(gl + 64);
        gl += ne4;
    };
    auto consume = [&](const f32x4* buf) {  // fma + 2 contiguous stores
        const float a = s_a[t];
        const float b = s_b[t];
        xv0 = a * xv0 + b * buf[0];
        xv1 = a * xv1 + b * buf[1];
        __builtin_nontemporal_store(xv0, st);
        __builtin_nontemporal_store(xv1, st + 64);
        st += ne4;
        ++t;
    };

    // Prologue: 4 planes in flight (8 loads, 8KB/wave).
    loadp(A); loadp(B); loadp(C); loadp(Dq);

    // 24 cycles x 4 planes = 96 consumed; planes 4..99 loaded on the fly.
    #pragma unroll 1
    for (int cyc = 0; cyc < (S_STEPS / DEPTH) - 1; ++cyc) {
        consume(A);  loadp(A);
        consume(B);  loadp(B);
        consume(C);  loadp(C);
        consume(Dq); loadp(Dq);
    }
    // Epilogue: planes 96..99.
    consume(A); consume(B); consume(C); consume(Dq);
}

extern "C" void kernel_launch(void* const* d_in, const int* in_sizes, int n_in,
                              void* d_out, int out_size, void* d_ws, size_t ws_size,
                              hipStream_t stream) {
    const float* x     = (const float*)d_in[0];   // (64,256,64)
    const float* noise = (const float*)d_in[1];   // (100,64,256,64)
    float* out         = (float*)d_out;           // (101,64,256,64)

    const int ne  = in_sizes[0];       // 1,048,576 floats per plane
    const int ne4 = ne / 4;            // 262,144 float4 per plane

    const int block = 256;
    const int grid  = ne4 / 512;       // 512 blocks (block tile = 8KB/plane)

    vpsde_fwd_kernel<<<grid, block, 0, stream>>>(
        (const f32x4*)x, (const f32x4*)noise, (f32x4*)out, ne4);
}